// Round 12
// baseline (487.932 us; speedup 1.0000x reference)
//
#include <hip/hip_runtime.h>

// GAT (3-layer) on MI355X.
// R11: two-pass CSR build. R10's one-kernel fill was latency/RMW-bound
// (83us, VALU 5%, hbm 21%) with an 8x-redundant edge-stream read (109MB
// logical) thrashing its own scatter window. Now: pass1 bins edges (read
// ONCE) into 8 per-partition buckets via LDS staging + coalesced copy-out;
// pass2 (XCD-affine) streams only its 1.6MB bucket while scattering into
// its 2.4MB L2-resident srclist window. Self-loops synthesized in pass2.

typedef unsigned short bfu;
typedef unsigned char u8;
typedef __attribute__((ext_vector_type(8))) short bf16x8;
typedef __attribute__((ext_vector_type(4))) float f32x4;
typedef __attribute__((ext_vector_type(2))) float f32x2;
typedef __attribute__((ext_vector_type(4))) int i32x4;

constexpr int N_NODES = 100000;
constexpr int E_IN    = 1600000;
constexpr float NEG   = 0.2f;
constexpr int P_XCD   = 8;
constexpr int PSZ     = N_NODES / P_XCD;  // 12500
constexpr int CAP     = 48;               // bucket slots/node
constexpr int AGG32_B = N_NODES / 32;     // 3125
constexpr int AGG128_B = N_NODES / 32;    // 3125 (8 dst/wave x 4 waves)
constexpr int GEMM_B  = (N_NODES + 63) / 64;        // 1563
constexpr int BIN_B   = (E_IN / 4 + 255) / 256;     // 1563
constexpr int TW_B    = (36864 + 255) / 256;        // 144
constexpr int BINCAP  = 272;              // LDS slots/bin (Binom(1024,1/8): P(>272)~1e-40)
constexpr int BCAP    = 231424;           // bucket capacity (mean 200k, sd ~430)
constexpr int MBLK    = BCAP / 1024;      // 226 scatter blocks per bucket
constexpr int SELF_B  = 13;               // self-loop blocks per partition (13*1024 >= 12500)
constexpr int SCAT_B  = P_XCD * (MBLK + SELF_B);   // 1912

__device__ inline bfu f2bf(float f) {
    union { float f; unsigned i; } c; c.f = f;
    unsigned x = c.i;
    return (bfu)((x + 0x7fffu + ((x >> 16) & 1u)) >> 16);
}
__device__ inline u8 f2fp8(float f) {
    return (u8)(__builtin_amdgcn_cvt_pk_fp8_f32(f, f, 0, false) & 0xff);
}

// ---------------- pass 1: bin edges by dst partition (+ transpose_w tail) ---

__global__ __launch_bounds__(256) void bin_w(const int* __restrict__ ei,
        uint2* __restrict__ gbkt, int* __restrict__ gcount,
        const float* __restrict__ W1, const float* __restrict__ W2,
        const float* __restrict__ W3, bfu* __restrict__ Wt1,
        bfu* __restrict__ Wt2, bfu* __restrict__ Wt3) {
    if (blockIdx.x >= BIN_B) {
        int idx = (blockIdx.x - BIN_B) * 256 + threadIdx.x;
        if (idx < 16384) {
            int k = idx >> 7, n = idx & 127;
            Wt1[n * 128 + k] = f2bf(W1[idx]);
        } else if (idx < 32768) {
            int r = idx - 16384;
            int k = r >> 7, n = r & 127;
            Wt2[n * 128 + k] = f2bf(W2[r]);
        } else if (idx < 36864) {
            int r = idx - 32768;
            int k = r >> 5, n = r & 31;
            Wt3[n * 128 + k] = f2bf(W3[r]);
        }
        return;
    }
    __shared__ uint2 bins[8][BINCAP];
    __shared__ int cnt[8];
    __shared__ int base[8];
    int tid = threadIdx.x;
    if (tid < 8) cnt[tid] = 0;
    __syncthreads();
    int e0 = (blockIdx.x * 256 + tid) * 4;
    if (e0 < E_IN) {   // E_IN % 4 == 0 -> all 4 valid
        i32x4 s4 = *(const i32x4*)(ei + e0);
        i32x4 d4 = *(const i32x4*)(ei + E_IN + e0);
        #pragma unroll
        for (int q = 0; q < 4; ++q) {
            int d = d4[q], s = s4[q];
            int p = (int)((unsigned)d / (unsigned)PSZ);
            int pos = atomicAdd(&cnt[p], 1);
            bins[p][pos] = make_uint2((unsigned)s, (unsigned)d);
        }
    }
    __syncthreads();
    if (tid < 8) base[tid] = atomicAdd(&gcount[tid], cnt[tid]);
    __syncthreads();
    #pragma unroll
    for (int p = 0; p < 8; ++p) {
        int c = cnt[p], b = base[p];
        for (int i = tid; i < c; i += 256)
            gbkt[(size_t)p * BCAP + b + i] = bins[p][i];
    }
}

// ---------------- pass 2: XCD-affine scatter (+ self loops) ----------------

__global__ __launch_bounds__(256) void scatter(const uint2* __restrict__ gbkt,
        const int* __restrict__ gcount, int* __restrict__ cursor,
        int* __restrict__ srclist) {
    int p = blockIdx.x & 7;
    int b = blockIdx.x >> 3;
    int tid = threadIdx.x;
    if (b < MBLK) {
        int cnt = gcount[p];
        int i0 = b * 1024 + tid * 4;
        if (i0 >= cnt) return;
        const uint2* src = gbkt + (size_t)p * BCAP;
        if (i0 + 4 <= cnt) {
            uint4 u01 = *(const uint4*)(src + i0);
            uint4 u23 = *(const uint4*)(src + i0 + 2);
            int pos;
            pos = atomicAdd(&cursor[u01.y], 1); if (pos < CAP) srclist[u01.y * CAP + pos] = (int)u01.x;
            pos = atomicAdd(&cursor[u01.w], 1); if (pos < CAP) srclist[u01.w * CAP + pos] = (int)u01.z;
            pos = atomicAdd(&cursor[u23.y], 1); if (pos < CAP) srclist[u23.y * CAP + pos] = (int)u23.x;
            pos = atomicAdd(&cursor[u23.w], 1); if (pos < CAP) srclist[u23.w * CAP + pos] = (int)u23.z;
        } else {
            for (int i = i0; i < cnt; ++i) {
                uint2 e = src[i];
                int pos = atomicAdd(&cursor[e.y], 1);
                if (pos < CAP) srclist[e.y * CAP + pos] = (int)e.x;
            }
        }
    } else {
        int bb = b - MBLK;   // 0..SELF_B-1
        int n0 = p * PSZ + bb * 1024 + tid * 4;
        int hi = (p + 1) * PSZ;
        #pragma unroll
        for (int q = 0; q < 4; ++q) {
            int n = n0 + q;
            if (n < hi) {
                int pos = atomicAdd(&cursor[n], 1);
                if (pos < CAP) srclist[n * CAP + pos] = n;
            }
        }
    }
}

// ---------------- MFMA GEMM + fused logits; fp8 h output --------------------
// C/D layout: row = quad*4+r, col = nt*16+m -> head = nt (HID=16), ch = m.

__device__ inline bf16x8 ldcvt_f32(const float* p) {
    float4 v0 = *(const float4*)p;
    float4 v1 = *(const float4*)(p + 4);
    bf16x8 a;
    a[0] = (short)f2bf(v0.x); a[1] = (short)f2bf(v0.y);
    a[2] = (short)f2bf(v0.z); a[3] = (short)f2bf(v0.w);
    a[4] = (short)f2bf(v1.x); a[5] = (short)f2bf(v1.y);
    a[6] = (short)f2bf(v1.z); a[7] = (short)f2bf(v1.w);
    return a;
}

template<int COUT, bool F32A, int H>
__global__ __launch_bounds__(256) void gemm_mfma(const void* __restrict__ Xg_,
                                                 const bfu* __restrict__ Wt,
                                                 const float* __restrict__ a_src,
                                                 const float* __restrict__ a_dst,
                                                 u8* __restrict__ Y,
                                                 float* __restrict__ als,
                                                 float* __restrict__ ald) {
    constexpr int NT = COUT / 16;
    int wid  = threadIdx.x >> 6;
    int lane = threadIdx.x & 63;
    int m = lane & 15, quad = lane >> 4;
    int rbase = (blockIdx.x * 4 + wid) * 16;
    if (rbase >= N_NODES) return;
    int rA = rbase + m; if (rA >= N_NODES) rA = N_NODES - 1;

    bf16x8 a0, a1, a2, a3;
    if constexpr (F32A) {
        const float* Ap = (const float*)Xg_ + (size_t)rA * 128 + quad * 8;
        a0 = ldcvt_f32(Ap);
        a1 = ldcvt_f32(Ap + 32);
        a2 = ldcvt_f32(Ap + 64);
        a3 = ldcvt_f32(Ap + 96);
    } else {
        const bfu* Ap = (const bfu*)Xg_ + (size_t)rA * 128 + quad * 8;
        a0 = *(const bf16x8*)(Ap);
        a1 = *(const bf16x8*)(Ap + 32);
        a2 = *(const bf16x8*)(Ap + 64);
        a3 = *(const bf16x8*)(Ap + 96);
    }

    const bfu* Bp = Wt + (size_t)m * 128 + quad * 8;
    f32x4 acc[NT];
    #pragma unroll
    for (int nt = 0; nt < NT; nt++) {
        const bfu* Bn = Bp + nt * 16 * 128;
        f32x4 c = {0.f, 0.f, 0.f, 0.f};
        c = __builtin_amdgcn_mfma_f32_16x16x32_bf16(a0, *(const bf16x8*)(Bn),      c, 0, 0, 0);
        c = __builtin_amdgcn_mfma_f32_16x16x32_bf16(a1, *(const bf16x8*)(Bn + 32), c, 0, 0, 0);
        c = __builtin_amdgcn_mfma_f32_16x16x32_bf16(a2, *(const bf16x8*)(Bn + 64), c, 0, 0, 0);
        c = __builtin_amdgcn_mfma_f32_16x16x32_bf16(a3, *(const bf16x8*)(Bn + 96), c, 0, 0, 0);
        acc[nt] = c;
    }

    #pragma unroll
    for (int nt = 0; nt < NT; nt++) {
        #pragma unroll
        for (int r = 0; r < 4; r++) {
            int row = rbase + quad * 4 + r;
            if (row < N_NODES)
                Y[(size_t)row * COUT + nt * 16 + m] = f2fp8(acc[nt][r]);
        }
    }

    if constexpr (H == 8) {
        #pragma unroll
        for (int nt = 0; nt < NT; nt++) {
            float as_ = a_src[nt * 16 + m];
            float ad_ = a_dst[nt * 16 + m];
            #pragma unroll
            for (int r = 0; r < 4; r++) {
                float vs = acc[nt][r] * as_;
                float vd = acc[nt][r] * ad_;
                #pragma unroll
                for (int mask = 1; mask < 16; mask <<= 1) {
                    vs += __shfl_xor(vs, mask);
                    vd += __shfl_xor(vd, mask);
                }
                int row = rbase + quad * 4 + r;
                if (m == 0 && row < N_NODES) {
                    als[row * 8 + nt] = vs;
                    ald[row * 8 + nt] = vd;
                }
            }
        }
    } else {  // H == 1, HID == 32, NT == 2
        float as0 = a_src[m], as1 = a_src[16 + m];
        float ad0 = a_dst[m], ad1 = a_dst[16 + m];
        #pragma unroll
        for (int r = 0; r < 4; r++) {
            float vs = acc[0][r] * as0 + acc[1][r] * as1;
            float vd = acc[0][r] * ad0 + acc[1][r] * ad1;
            #pragma unroll
            for (int mask = 1; mask < 16; mask <<= 1) {
                vs += __shfl_xor(vs, mask);
                vd += __shfl_xor(vd, mask);
            }
            int row = rbase + quad * 4 + r;
            if (m == 0 && row < N_NODES) {
                als[row] = vs;
                ald[row] = vd;
            }
        }
    }
}

// ---------------- aggregation ----------------
// agg128: 8 dst per wave; 8 lanes per dst; lane owns 16 fp8 ch = one head.

__device__ inline void unpack_fma(uint4 u, float w, float* a) {
    f32x2 p;
    p = __builtin_amdgcn_cvt_pk_f32_fp8((int)u.x, false); a[0]=fmaf(w,p[0],a[0]);  a[1]=fmaf(w,p[1],a[1]);
    p = __builtin_amdgcn_cvt_pk_f32_fp8((int)u.x, true);  a[2]=fmaf(w,p[0],a[2]);  a[3]=fmaf(w,p[1],a[3]);
    p = __builtin_amdgcn_cvt_pk_f32_fp8((int)u.y, false); a[4]=fmaf(w,p[0],a[4]);  a[5]=fmaf(w,p[1],a[5]);
    p = __builtin_amdgcn_cvt_pk_f32_fp8((int)u.y, true);  a[6]=fmaf(w,p[0],a[6]);  a[7]=fmaf(w,p[1],a[7]);
    p = __builtin_amdgcn_cvt_pk_f32_fp8((int)u.z, false); a[8]=fmaf(w,p[0],a[8]);  a[9]=fmaf(w,p[1],a[9]);
    p = __builtin_amdgcn_cvt_pk_f32_fp8((int)u.z, true);  a[10]=fmaf(w,p[0],a[10]); a[11]=fmaf(w,p[1],a[11]);
    p = __builtin_amdgcn_cvt_pk_f32_fp8((int)u.w, false); a[12]=fmaf(w,p[0],a[12]); a[13]=fmaf(w,p[1],a[13]);
    p = __builtin_amdgcn_cvt_pk_f32_fp8((int)u.w, true);  a[14]=fmaf(w,p[0],a[14]); a[15]=fmaf(w,p[1],a[15]);
}

__global__ __launch_bounds__(256) void agg128(const u8* __restrict__ Hb,
        const float* __restrict__ als, const float* __restrict__ ald,
        const int* __restrict__ deg, const int* __restrict__ srclist,
        const float* __restrict__ bias, bfu* __restrict__ out) {
    int wave = blockIdx.x * 4 + (threadIdx.x >> 6);
    int lane = threadIdx.x & 63;
    int sub  = lane >> 3;           // 8 dst per wave
    int li   = lane & 7;            // lane within dst == head
    int d    = wave * 8 + sub;      // exact: N_NODES % 32 == 0
    int c0   = li * 16;
    float ad = ald[d * 8 + li];
    const int* sl = srclist + d * CAP;
    int n = deg[d]; n = n < CAP ? n : CAP;
    float a[16];
    #pragma unroll
    for (int k = 0; k < 16; ++k) a[k] = 0.f;
    float den = 0.f;
    int j = 0;
    for (; j + 2 <= n; j += 2) {
        int s0 = sl[j], s1 = sl[j + 1];
        uint4 u0 = *(const uint4*)(Hb + (size_t)s0 * 128 + c0);
        uint4 u1 = *(const uint4*)(Hb + (size_t)s1 * 128 + c0);
        float x0 = als[s0 * 8 + li], x1 = als[s1 * 8 + li];
        float l0 = x0 + ad; l0 = fmaxf(l0, NEG * l0); float w0 = __expf(l0);
        float l1 = x1 + ad; l1 = fmaxf(l1, NEG * l1); float w1 = __expf(l1);
        den += w0 + w1;
        unpack_fma(u0, w0, a);
        unpack_fma(u1, w1, a);
    }
    if (j < n) {
        int s0 = sl[j];
        uint4 u0 = *(const uint4*)(Hb + (size_t)s0 * 128 + c0);
        float x0 = als[s0 * 8 + li];
        float l0 = x0 + ad; l0 = fmaxf(l0, NEG * l0); float w0 = __expf(l0);
        den += w0;
        unpack_fma(u0, w0, a);
    }
    float r = 1.f / den;
    unsigned dw[8];
    #pragma unroll
    for (int k = 0; k < 8; ++k) {
        float e0 = fmaxf(fmaf(a[2*k],   r, bias[c0 + 2*k]),   0.f);
        float e1 = fmaxf(fmaf(a[2*k+1], r, bias[c0 + 2*k+1]), 0.f);
        dw[k] = (unsigned)f2bf(e0) | ((unsigned)f2bf(e1) << 16);
    }
    uint4 st0 = {dw[0], dw[1], dw[2], dw[3]};
    uint4 st1 = {dw[4], dw[5], dw[6], dw[7]};
    *(uint4*)&out[(size_t)d * 128 + c0]     = st0;
    *(uint4*)&out[(size_t)d * 128 + c0 + 8] = st1;
}

// agg32 + fused mean pool: 8 dst/wave, 8 lanes/dst, lane owns 4 ch (4B fp8).
__global__ __launch_bounds__(256) void agg32(const u8* __restrict__ Hb,
        const float* __restrict__ als, const float* __restrict__ ald,
        const int* __restrict__ deg, const int* __restrict__ srclist,
        const float* __restrict__ bias, float* __restrict__ outp) {
    __shared__ float lds[4][32];
    int t    = threadIdx.x;
    int wid  = t >> 6;
    int lane = t & 63;
    int sub  = lane >> 3;
    int li   = lane & 7;
    int d    = blockIdx.x * 32 + wid * 8 + sub;   // exact
    int c0 = li * 4;
    float adv = ald[d];
    const int* sl = srclist + d * CAP;
    int n = deg[d]; n = n < CAP ? n : CAP;
    float a0=0.f,a1=0.f,a2=0.f,a3=0.f,den=0.f;
    int j = 0;
    for (; j + 4 <= n; j += 4) {
        int s0 = sl[j], s1 = sl[j+1], s2 = sl[j+2], s3 = sl[j+3];
        unsigned u0 = *(const unsigned*)(Hb + (size_t)s0 * 32 + c0);
        unsigned u1 = *(const unsigned*)(Hb + (size_t)s1 * 32 + c0);
        unsigned u2 = *(const unsigned*)(Hb + (size_t)s2 * 32 + c0);
        unsigned u3 = *(const unsigned*)(Hb + (size_t)s3 * 32 + c0);
        float x0 = als[s0], x1 = als[s1], x2 = als[s2], x3 = als[s3];
        float l0 = x0 + adv; l0 = fmaxf(l0, NEG*l0); float w0 = __expf(l0);
        float l1 = x1 + adv; l1 = fmaxf(l1, NEG*l1); float w1 = __expf(l1);
        float l2 = x2 + adv; l2 = fmaxf(l2, NEG*l2); float w2 = __expf(l2);
        float l3 = x3 + adv; l3 = fmaxf(l3, NEG*l3); float w3 = __expf(l3);
        den += (w0 + w1) + (w2 + w3);
        f32x2 p;
        p = __builtin_amdgcn_cvt_pk_f32_fp8((int)u0, false); a0=fmaf(w0,p[0],a0); a1=fmaf(w0,p[1],a1);
        p = __builtin_amdgcn_cvt_pk_f32_fp8((int)u0, true);  a2=fmaf(w0,p[0],a2); a3=fmaf(w0,p[1],a3);
        p = __builtin_amdgcn_cvt_pk_f32_fp8((int)u1, false); a0=fmaf(w1,p[0],a0); a1=fmaf(w1,p[1],a1);
        p = __builtin_amdgcn_cvt_pk_f32_fp8((int)u1, true);  a2=fmaf(w1,p[0],a2); a3=fmaf(w1,p[1],a3);
        p = __builtin_amdgcn_cvt_pk_f32_fp8((int)u2, false); a0=fmaf(w2,p[0],a0); a1=fmaf(w2,p[1],a1);
        p = __builtin_amdgcn_cvt_pk_f32_fp8((int)u2, true);  a2=fmaf(w2,p[0],a2); a3=fmaf(w2,p[1],a3);
        p = __builtin_amdgcn_cvt_pk_f32_fp8((int)u3, false); a0=fmaf(w3,p[0],a0); a1=fmaf(w3,p[1],a1);
        p = __builtin_amdgcn_cvt_pk_f32_fp8((int)u3, true);  a2=fmaf(w3,p[0],a2); a3=fmaf(w3,p[1],a3);
    }
    for (; j < n; ++j) {
        int s0 = sl[j];
        unsigned u0 = *(const unsigned*)(Hb + (size_t)s0 * 32 + c0);
        float x0 = als[s0];
        float l0 = x0 + adv; l0 = fmaxf(l0, NEG*l0); float w0 = __expf(l0);
        den += w0;
        f32x2 p;
        p = __builtin_amdgcn_cvt_pk_f32_fp8((int)u0, false); a0=fmaf(w0,p[0],a0); a1=fmaf(w0,p[1],a1);
        p = __builtin_amdgcn_cvt_pk_f32_fp8((int)u0, true);  a2=fmaf(w0,p[0],a2); a3=fmaf(w0,p[1],a3);
    }
    float r = 1.f / den;
    float4 bv = *(const float4*)&bias[c0];
    float o0 = fmaf(a0, r, bv.x), o1 = fmaf(a1, r, bv.y);
    float o2 = fmaf(a2, r, bv.z), o3 = fmaf(a3, r, bv.w);
    #pragma unroll
    for (int mask = 8; mask < 64; mask <<= 1) {
        o0 += __shfl_xor(o0, mask);
        o1 += __shfl_xor(o1, mask);
        o2 += __shfl_xor(o2, mask);
        o3 += __shfl_xor(o3, mask);
    }
    if (sub == 0) {
        lds[wid][c0]     = o0;
        lds[wid][c0 + 1] = o1;
        lds[wid][c0 + 2] = o2;
        lds[wid][c0 + 3] = o3;
    }
    __syncthreads();
    if (t < 32)
        atomicAdd(&outp[t],
            (lds[0][t] + lds[1][t] + lds[2][t] + lds[3][t]) * (1.0f / N_NODES));
}

// ---------------- launch ----------------

extern "C" void kernel_launch(void* const* d_in, const int* in_sizes, int n_in,
                              void* d_out, int out_size, void* d_ws, size_t ws_size,
                              hipStream_t stream) {
    (void)in_sizes; (void)n_in; (void)out_size; (void)ws_size;
    const float* x   = (const float*)d_in[0];
    const int*   ei  = (const int*)d_in[1];
    const float* W1  = (const float*)d_in[2];
    const float* as1 = (const float*)d_in[3];
    const float* ad1 = (const float*)d_in[4];
    const float* b1  = (const float*)d_in[5];
    const float* W2  = (const float*)d_in[6];
    const float* as2 = (const float*)d_in[7];
    const float* ad2 = (const float*)d_in[8];
    const float* b2  = (const float*)d_in[9];
    const float* W3  = (const float*)d_in[10];
    const float* as3 = (const float*)d_in[11];
    const float* ad3 = (const float*)d_in[12];
    const float* b3  = (const float*)d_in[13];

    char* ws = (char*)d_ws;
    size_t off = 0;
    auto carve = [&](size_t bytes) { void* p = ws + off; off += (bytes + 255) & ~size_t(255); return p; };
    u8*    bufH    = (u8*)carve(size_t(N_NODES) * 128);        // h (fp8 e4m3)
    bfu*   bufF    = (bfu*)carve(size_t(N_NODES) * 128 * 2);   // agg out (bf16)
    float* als     = (float*)carve(size_t(N_NODES) * 8 * 4);
    float* ald     = (float*)carve(size_t(N_NODES) * 8 * 4);
    int*   cursor  = (int*)carve(size_t(N_NODES) * 4);
    int*   gcount  = (int*)carve(8 * 4);
    bfu*   Wt1     = (bfu*)carve(128 * 128 * 2);
    bfu*   Wt2     = (bfu*)carve(128 * 128 * 2);
    bfu*   Wt3     = (bfu*)carve(32 * 128 * 2);
    int*   srclist = (int*)carve(size_t(N_NODES) * CAP * 4);
    uint2* gbkt    = (uint2*)carve(size_t(P_XCD) * BCAP * 8);

    hipMemsetAsync(cursor, 0, size_t(N_NODES) * 4, stream);
    hipMemsetAsync(gcount, 0, 8 * 4, stream);
    hipMemsetAsync(d_out, 0, 32 * 4, stream);

    // two-pass CSR build (+ W transpose tail in pass 1)
    bin_w<<<BIN_B + TW_B, 256, 0, stream>>>(ei, gbkt, gcount, W1, W2, W3, Wt1, Wt2, Wt3);
    scatter<<<SCAT_B, 256, 0, stream>>>(gbkt, gcount, cursor, srclist);

    // layer 1 (fp32 A, cvt in register)
    gemm_mfma<128, true, 8><<<GEMM_B, 256, 0, stream>>>(x, Wt1, as1, ad1, bufH, als, ald);
    agg128<<<AGG128_B, 256, 0, stream>>>(bufH, als, ald, cursor, srclist, b1, bufF);

    // layer 2
    gemm_mfma<128, false, 8><<<GEMM_B, 256, 0, stream>>>(bufF, Wt2, as2, ad2, bufH, als, ald);
    agg128<<<AGG128_B, 256, 0, stream>>>(bufH, als, ald, cursor, srclist, b2, bufF);

    // layer 3
    gemm_mfma<32, false, 1><<<GEMM_B, 256, 0, stream>>>(bufF, Wt3, as3, ad3, bufH, als, ald);
    agg32<<<AGG32_B, 256, 0, stream>>>(bufH, als, ald, cursor, srclist, b3, (float*)d_out);
}

// Round 13
// 432.742 us; speedup vs baseline: 1.1275x; 1.1275x over previous
//
#include <hip/hip_runtime.h>

// GAT (3-layer) on MI355X.
// R12: (a) logits folded into the GEMM as 16 extra B columns (ws/wd =
//      W·a_src per head, precomputed bf16): R11 revealed gemm_mfma at 73us
//      with EVERYTHING idle -- the R7 shuffle epilogue (256 ds_bpermute/wave
//      in 4-deep chains) was serializing the tiny 6252-wave grid. Epilogue
//      is now 8 plain stores. (b) CSR build reverted to R8's proven
//      single-pass partitioned fill (72us), CAP=64, prep as tail blocks.

typedef unsigned short bfu;
typedef unsigned char u8;
typedef __attribute__((ext_vector_type(8))) short bf16x8;
typedef __attribute__((ext_vector_type(4))) float f32x4;
typedef __attribute__((ext_vector_type(2))) float f32x2;

constexpr int N_NODES = 100000;
constexpr int E_IN    = 1600000;
constexpr int E_TOT   = E_IN + N_NODES;   // + self loops
constexpr float NEG   = 0.2f;
constexpr int P_XCD   = 8;
constexpr int PSZ     = N_NODES / P_XCD;  // 12500
constexpr int CAP     = 64;               // bucket slots/node (Poisson(16)+1)
constexpr int AGG32_B = N_NODES / 32;     // 3125
constexpr int AGG128_B = N_NODES / 32;    // 3125 (8 dst/wave x 4 waves)
constexpr int GEMM_B  = (N_NODES + 63) / 64;        // 1563
constexpr int EDGE_B4 = (E_TOT / 4 + 255) / 256;    // 1661
constexpr int FILL_B  = EDGE_B4 * P_XCD;            // 13288
constexpr int PREP_ITEMS = 43008;
constexpr int PREP_B  = (PREP_ITEMS + 255) / 256;   // 168

__device__ inline bfu f2bf(float f) {
    union { float f; unsigned i; } c; c.f = f;
    unsigned x = c.i;
    return (bfu)((x + 0x7fffu + ((x >> 16) & 1u)) >> 16);
}
__device__ inline u8 f2fp8(float f) {
    return (u8)(__builtin_amdgcn_cvt_pk_fp8_f32(f, f, 0, false) & 0xff);
}

// ---------------- prep: W^T + folded logit columns (bf16) -------------------
// WtX1/WtX2: 144 rows x 128 k  (rows 0-127 = W^T; 128-135 = ws; 136-143 = wd)
// WtX3:      48 rows x 128 k   (rows 0-31 = W3^T; 32 = ws3; 33 = wd3; 34-47 = 0)

__device__ inline void prep_body(int idx,
        const float* __restrict__ W1, const float* __restrict__ W2,
        const float* __restrict__ W3,
        const float* __restrict__ as1, const float* __restrict__ ad1,
        const float* __restrict__ as2, const float* __restrict__ ad2,
        const float* __restrict__ as3, const float* __restrict__ ad3,
        bfu* __restrict__ WtX1, bfu* __restrict__ WtX2, bfu* __restrict__ WtX3) {
    if (idx < 16384) {
        int k = idx >> 7, n = idx & 127;
        WtX1[n * 128 + k] = f2bf(W1[idx]);
    } else if (idx < 32768) {
        int r = idx - 16384;
        int k = r >> 7, n = r & 127;
        WtX2[n * 128 + k] = f2bf(W2[r]);
    } else if (idx < 36864) {
        int r = idx - 32768;
        int k = r >> 5, n = r & 31;
        WtX3[n * 128 + k] = f2bf(W3[r]);
    } else if (idx < 38912) {          // layer-1 ws/wd: 2 x 8h x 128k
        int r = idx - 36864;
        int sd = r >> 10, rr = r & 1023;
        int h = rr >> 7, k = rr & 127;
        const float* a = sd ? ad1 : as1;
        float v = 0.f;
        #pragma unroll
        for (int c = 0; c < 16; ++c) v += W1[k * 128 + h * 16 + c] * a[h * 16 + c];
        WtX1[(128 + sd * 8 + h) * 128 + k] = f2bf(v);
    } else if (idx < 40960) {          // layer-2 ws/wd
        int r = idx - 38912;
        int sd = r >> 10, rr = r & 1023;
        int h = rr >> 7, k = rr & 127;
        const float* a = sd ? ad2 : as2;
        float v = 0.f;
        #pragma unroll
        for (int c = 0; c < 16; ++c) v += W2[k * 128 + h * 16 + c] * a[h * 16 + c];
        WtX2[(128 + sd * 8 + h) * 128 + k] = f2bf(v);
    } else if (idx < 41216) {          // layer-3 ws/wd: 2 x 128k
        int r = idx - 40960;
        int sd = r >> 7, k = r & 127;
        const float* a = sd ? ad3 : as3;
        float v = 0.f;
        #pragma unroll
        for (int c = 0; c < 32; ++c) v += W3[k * 32 + c] * a[c];
        WtX3[(32 + sd) * 128 + k] = f2bf(v);
    } else if (idx < 43008) {          // zero rows 34-47 of WtX3
        WtX3[34 * 128 + (idx - 41216)] = 0;
    }
}

// ---------------- fill (dst-partitioned, R8-proven) + prep tail -------------

__global__ __launch_bounds__(256) void fill_prep(const int* __restrict__ ei,
        int* __restrict__ cursor, int* __restrict__ srclist,
        const float* __restrict__ W1, const float* __restrict__ W2,
        const float* __restrict__ W3,
        const float* __restrict__ as1, const float* __restrict__ ad1,
        const float* __restrict__ as2, const float* __restrict__ ad2,
        const float* __restrict__ as3, const float* __restrict__ ad3,
        bfu* __restrict__ WtX1, bfu* __restrict__ WtX2, bfu* __restrict__ WtX3) {
    if (blockIdx.x >= FILL_B) {
        int idx = (blockIdx.x - FILL_B) * 256 + threadIdx.x;
        prep_body(idx, W1, W2, W3, as1, ad1, as2, ad2, as3, ad3, WtX1, WtX2, WtX3);
        return;
    }
    int p = blockIdx.x & 7;
    int b = blockIdx.x >> 3;
    int lo = p * PSZ, hi = lo + PSZ;
    int e0 = (b * 256 + threadIdx.x) * 4;
    if (e0 >= E_TOT) return;
    bool self = e0 >= E_IN;
    int4 d4;
    if (!self) d4 = *(const int4*)&ei[E_IN + e0];
    else { int bb = e0 - E_IN; d4 = make_int4(bb, bb + 1, bb + 2, bb + 3); }
    int dd[4] = {d4.x, d4.y, d4.z, d4.w};
    #pragma unroll
    for (int q = 0; q < 4; ++q) {
        int d = dd[q];
        if (d >= lo && d < hi) {
            int s = self ? (e0 - E_IN + q) : ei[e0 + q];
            int pos = atomicAdd(&cursor[d], 1);
            if (pos < CAP) srclist[d * CAP + pos] = s;
        }
    }
}

// ---------------- MFMA GEMM, logits as extra B-tile; fp8 h output -----------
// C/D layout: row = quad*4+r, col = nt*16+m.

__device__ inline bf16x8 ldcvt_f32(const float* p) {
    float4 v0 = *(const float4*)p;
    float4 v1 = *(const float4*)(p + 4);
    bf16x8 a;
    a[0] = (short)f2bf(v0.x); a[1] = (short)f2bf(v0.y);
    a[2] = (short)f2bf(v0.z); a[3] = (short)f2bf(v0.w);
    a[4] = (short)f2bf(v1.x); a[5] = (short)f2bf(v1.y);
    a[6] = (short)f2bf(v1.z); a[7] = (short)f2bf(v1.w);
    return a;
}

// NTO = feature tiles (8 -> COUT=128/H=8; 2 -> COUT=32/H=1). Tile NTO = logits.
template<int NTO, bool F32A>
__global__ __launch_bounds__(256) void gemm_mfma(const void* __restrict__ Xg_,
                                                 const bfu* __restrict__ Wt,
                                                 u8* __restrict__ Y,
                                                 float* __restrict__ als,
                                                 float* __restrict__ ald) {
    constexpr int COUT = NTO * 16;
    int wid  = threadIdx.x >> 6;
    int lane = threadIdx.x & 63;
    int m = lane & 15, quad = lane >> 4;
    int rbase = (blockIdx.x * 4 + wid) * 16;
    if (rbase >= N_NODES) return;
    int rA = rbase + m; if (rA >= N_NODES) rA = N_NODES - 1;

    bf16x8 a0, a1, a2, a3;
    if constexpr (F32A) {
        const float* Ap = (const float*)Xg_ + (size_t)rA * 128 + quad * 8;
        a0 = ldcvt_f32(Ap);
        a1 = ldcvt_f32(Ap + 32);
        a2 = ldcvt_f32(Ap + 64);
        a3 = ldcvt_f32(Ap + 96);
    } else {
        const bfu* Ap = (const bfu*)Xg_ + (size_t)rA * 128 + quad * 8;
        a0 = *(const bf16x8*)(Ap);
        a1 = *(const bf16x8*)(Ap + 32);
        a2 = *(const bf16x8*)(Ap + 64);
        a3 = *(const bf16x8*)(Ap + 96);
    }

    const bfu* Bp = Wt + (size_t)m * 128 + quad * 8;
    f32x4 acc[NTO + 1];
    #pragma unroll
    for (int nt = 0; nt <= NTO; nt++) {
        const bfu* Bn = Bp + nt * 16 * 128;
        f32x4 c = {0.f, 0.f, 0.f, 0.f};
        c = __builtin_amdgcn_mfma_f32_16x16x32_bf16(a0, *(const bf16x8*)(Bn),      c, 0, 0, 0);
        c = __builtin_amdgcn_mfma_f32_16x16x32_bf16(a1, *(const bf16x8*)(Bn + 32), c, 0, 0, 0);
        c = __builtin_amdgcn_mfma_f32_16x16x32_bf16(a2, *(const bf16x8*)(Bn + 64), c, 0, 0, 0);
        c = __builtin_amdgcn_mfma_f32_16x16x32_bf16(a3, *(const bf16x8*)(Bn + 96), c, 0, 0, 0);
        acc[nt] = c;
    }

    // fp8 feature store
    #pragma unroll
    for (int nt = 0; nt < NTO; nt++) {
        #pragma unroll
        for (int r = 0; r < 4; r++) {
            int row = rbase + quad * 4 + r;
            if (row < N_NODES)
                Y[(size_t)row * COUT + nt * 16 + m] = f2fp8(acc[nt][r]);
        }
    }
    // logits store from tile NTO
    #pragma unroll
    for (int r = 0; r < 4; r++) {
        int row = rbase + quad * 4 + r;
        if (row >= N_NODES) continue;
        float v = acc[NTO][r];
        if constexpr (NTO == 8) {
            if (m < 8) als[row * 8 + m] = v;
            else       ald[row * 8 + (m - 8)] = v;
        } else {
            if (m == 0) als[row] = v;
            else if (m == 1) ald[row] = v;
        }
    }
}

// ---------------- aggregation ----------------
// agg128: 8 dst per wave; 8 lanes per dst; lane owns 16 fp8 ch = one head.

__device__ inline void unpack_fma(uint4 u, float w, float* a) {
    f32x2 p;
    p = __builtin_amdgcn_cvt_pk_f32_fp8((int)u.x, false); a[0]=fmaf(w,p[0],a[0]);  a[1]=fmaf(w,p[1],a[1]);
    p = __builtin_amdgcn_cvt_pk_f32_fp8((int)u.x, true);  a[2]=fmaf(w,p[0],a[2]);  a[3]=fmaf(w,p[1],a[3]);
    p = __builtin_amdgcn_cvt_pk_f32_fp8((int)u.y, false); a[4]=fmaf(w,p[0],a[4]);  a[5]=fmaf(w,p[1],a[5]);
    p = __builtin_amdgcn_cvt_pk_f32_fp8((int)u.y, true);  a[6]=fmaf(w,p[0],a[6]);  a[7]=fmaf(w,p[1],a[7]);
    p = __builtin_amdgcn_cvt_pk_f32_fp8((int)u.z, false); a[8]=fmaf(w,p[0],a[8]);  a[9]=fmaf(w,p[1],a[9]);
    p = __builtin_amdgcn_cvt_pk_f32_fp8((int)u.z, true);  a[10]=fmaf(w,p[0],a[10]); a[11]=fmaf(w,p[1],a[11]);
    p = __builtin_amdgcn_cvt_pk_f32_fp8((int)u.w, false); a[12]=fmaf(w,p[0],a[12]); a[13]=fmaf(w,p[1],a[13]);
    p = __builtin_amdgcn_cvt_pk_f32_fp8((int)u.w, true);  a[14]=fmaf(w,p[0],a[14]); a[15]=fmaf(w,p[1],a[15]);
}

__global__ __launch_bounds__(256) void agg128(const u8* __restrict__ Hb,
        const float* __restrict__ als, const float* __restrict__ ald,
        const int* __restrict__ deg, const int* __restrict__ srclist,
        const float* __restrict__ bias, bfu* __restrict__ out) {
    int wave = blockIdx.x * 4 + (threadIdx.x >> 6);
    int lane = threadIdx.x & 63;
    int sub  = lane >> 3;           // 8 dst per wave
    int li   = lane & 7;            // lane within dst == head
    int d    = wave * 8 + sub;      // exact: N_NODES % 32 == 0
    int c0   = li * 16;
    float ad = ald[d * 8 + li];
    const int* sl = srclist + d * CAP;
    int n = deg[d]; n = n < CAP ? n : CAP;
    float a[16];
    #pragma unroll
    for (int k = 0; k < 16; ++k) a[k] = 0.f;
    float den = 0.f;
    int j = 0;
    for (; j + 2 <= n; j += 2) {
        int s0 = sl[j], s1 = sl[j + 1];
        uint4 u0 = *(const uint4*)(Hb + (size_t)s0 * 128 + c0);
        uint4 u1 = *(const uint4*)(Hb + (size_t)s1 * 128 + c0);
        float x0 = als[s0 * 8 + li], x1 = als[s1 * 8 + li];
        float l0 = x0 + ad; l0 = fmaxf(l0, NEG * l0); float w0 = __expf(l0);
        float l1 = x1 + ad; l1 = fmaxf(l1, NEG * l1); float w1 = __expf(l1);
        den += w0 + w1;
        unpack_fma(u0, w0, a);
        unpack_fma(u1, w1, a);
    }
    if (j < n) {
        int s0 = sl[j];
        uint4 u0 = *(const uint4*)(Hb + (size_t)s0 * 128 + c0);
        float x0 = als[s0 * 8 + li];
        float l0 = x0 + ad; l0 = fmaxf(l0, NEG * l0); float w0 = __expf(l0);
        den += w0;
        unpack_fma(u0, w0, a);
    }
    float r = 1.f / den;
    unsigned dw[8];
    #pragma unroll
    for (int k = 0; k < 8; ++k) {
        float e0 = fmaxf(fmaf(a[2*k],   r, bias[c0 + 2*k]),   0.f);
        float e1 = fmaxf(fmaf(a[2*k+1], r, bias[c0 + 2*k+1]), 0.f);
        dw[k] = (unsigned)f2bf(e0) | ((unsigned)f2bf(e1) << 16);
    }
    uint4 st0 = {dw[0], dw[1], dw[2], dw[3]};
    uint4 st1 = {dw[4], dw[5], dw[6], dw[7]};
    *(uint4*)&out[(size_t)d * 128 + c0]     = st0;
    *(uint4*)&out[(size_t)d * 128 + c0 + 8] = st1;
}

// agg32 + fused mean pool: 8 dst/wave, 8 lanes/dst, lane owns 4 ch (4B fp8).
__global__ __launch_bounds__(256) void agg32(const u8* __restrict__ Hb,
        const float* __restrict__ als, const float* __restrict__ ald,
        const int* __restrict__ deg, const int* __restrict__ srclist,
        const float* __restrict__ bias, float* __restrict__ outp) {
    __shared__ float lds[4][32];
    int t    = threadIdx.x;
    int wid  = t >> 6;
    int lane = t & 63;
    int sub  = lane >> 3;
    int li   = lane & 7;
    int d    = blockIdx.x * 32 + wid * 8 + sub;   // exact
    int c0 = li * 4;
    float adv = ald[d];
    const int* sl = srclist + d * CAP;
    int n = deg[d]; n = n < CAP ? n : CAP;
    float a0=0.f,a1=0.f,a2=0.f,a3=0.f,den=0.f;
    int j = 0;
    for (; j + 4 <= n; j += 4) {
        int s0 = sl[j], s1 = sl[j+1], s2 = sl[j+2], s3 = sl[j+3];
        unsigned u0 = *(const unsigned*)(Hb + (size_t)s0 * 32 + c0);
        unsigned u1 = *(const unsigned*)(Hb + (size_t)s1 * 32 + c0);
        unsigned u2 = *(const unsigned*)(Hb + (size_t)s2 * 32 + c0);
        unsigned u3 = *(const unsigned*)(Hb + (size_t)s3 * 32 + c0);
        float x0 = als[s0], x1 = als[s1], x2 = als[s2], x3 = als[s3];
        float l0 = x0 + adv; l0 = fmaxf(l0, NEG*l0); float w0 = __expf(l0);
        float l1 = x1 + adv; l1 = fmaxf(l1, NEG*l1); float w1 = __expf(l1);
        float l2 = x2 + adv; l2 = fmaxf(l2, NEG*l2); float w2 = __expf(l2);
        float l3 = x3 + adv; l3 = fmaxf(l3, NEG*l3); float w3 = __expf(l3);
        den += (w0 + w1) + (w2 + w3);
        f32x2 p;
        p = __builtin_amdgcn_cvt_pk_f32_fp8((int)u0, false); a0=fmaf(w0,p[0],a0); a1=fmaf(w0,p[1],a1);
        p = __builtin_amdgcn_cvt_pk_f32_fp8((int)u0, true);  a2=fmaf(w0,p[0],a2); a3=fmaf(w0,p[1],a3);
        p = __builtin_amdgcn_cvt_pk_f32_fp8((int)u1, false); a0=fmaf(w1,p[0],a0); a1=fmaf(w1,p[1],a1);
        p = __builtin_amdgcn_cvt_pk_f32_fp8((int)u1, true);  a2=fmaf(w1,p[0],a2); a3=fmaf(w1,p[1],a3);
        p = __builtin_amdgcn_cvt_pk_f32_fp8((int)u2, false); a0=fmaf(w2,p[0],a0); a1=fmaf(w2,p[1],a1);
        p = __builtin_amdgcn_cvt_pk_f32_fp8((int)u2, true);  a2=fmaf(w2,p[0],a2); a3=fmaf(w2,p[1],a3);
        p = __builtin_amdgcn_cvt_pk_f32_fp8((int)u3, false); a0=fmaf(w3,p[0],a0); a1=fmaf(w3,p[1],a1);
        p = __builtin_amdgcn_cvt_pk_f32_fp8((int)u3, true);  a2=fmaf(w3,p[0],a2); a3=fmaf(w3,p[1],a3);
    }
    for (; j < n; ++j) {
        int s0 = sl[j];
        unsigned u0 = *(const unsigned*)(Hb + (size_t)s0 * 32 + c0);
        float x0 = als[s0];
        float l0 = x0 + adv; l0 = fmaxf(l0, NEG*l0); float w0 = __expf(l0);
        den += w0;
        f32x2 p;
        p = __builtin_amdgcn_cvt_pk_f32_fp8((int)u0, false); a0=fmaf(w0,p[0],a0); a1=fmaf(w0,p[1],a1);
        p = __builtin_amdgcn_cvt_pk_f32_fp8((int)u0, true);  a2=fmaf(w0,p[0],a2); a3=fmaf(w0,p[1],a3);
    }
    float r = 1.f / den;
    float4 bv = *(const float4*)&bias[c0];
    float o0 = fmaf(a0, r, bv.x), o1 = fmaf(a1, r, bv.y);
    float o2 = fmaf(a2, r, bv.z), o3 = fmaf(a3, r, bv.w);
    #pragma unroll
    for (int mask = 8; mask < 64; mask <<= 1) {
        o0 += __shfl_xor(o0, mask);
        o1 += __shfl_xor(o1, mask);
        o2 += __shfl_xor(o2, mask);
        o3 += __shfl_xor(o3, mask);
    }
    if (sub == 0) {
        lds[wid][c0]     = o0;
        lds[wid][c0 + 1] = o1;
        lds[wid][c0 + 2] = o2;
        lds[wid][c0 + 3] = o3;
    }
    __syncthreads();
    if (t < 32)
        atomicAdd(&outp[t],
            (lds[0][t] + lds[1][t] + lds[2][t] + lds[3][t]) * (1.0f / N_NODES));
}

// ---------------- launch ----------------

extern "C" void kernel_launch(void* const* d_in, const int* in_sizes, int n_in,
                              void* d_out, int out_size, void* d_ws, size_t ws_size,
                              hipStream_t stream) {
    (void)in_sizes; (void)n_in; (void)out_size; (void)ws_size;
    const float* x   = (const float*)d_in[0];
    const int*   ei  = (const int*)d_in[1];
    const float* W1  = (const float*)d_in[2];
    const float* as1 = (const float*)d_in[3];
    const float* ad1 = (const float*)d_in[4];
    const float* b1  = (const float*)d_in[5];
    const float* W2  = (const float*)d_in[6];
    const float* as2 = (const float*)d_in[7];
    const float* ad2 = (const float*)d_in[8];
    const float* b2  = (const float*)d_in[9];
    const float* W3  = (const float*)d_in[10];
    const float* as3 = (const float*)d_in[11];
    const float* ad3 = (const float*)d_in[12];
    const float* b3  = (const float*)d_in[13];

    char* ws = (char*)d_ws;
    size_t off = 0;
    auto carve = [&](size_t bytes) { void* p = ws + off; off += (bytes + 255) & ~size_t(255); return p; };
    u8*    bufH    = (u8*)carve(size_t(N_NODES) * 128);        // h (fp8 e4m3)
    bfu*   bufF    = (bfu*)carve(size_t(N_NODES) * 128 * 2);   // agg out (bf16)
    float* als     = (float*)carve(size_t(N_NODES) * 8 * 4);
    float* ald     = (float*)carve(size_t(N_NODES) * 8 * 4);
    int*   cursor  = (int*)carve(size_t(N_NODES) * 4);
    bfu*   WtX1    = (bfu*)carve(144 * 128 * 2);
    bfu*   WtX2    = (bfu*)carve(144 * 128 * 2);
    bfu*   WtX3    = (bfu*)carve(48 * 128 * 2);
    int*   srclist = (int*)carve(size_t(N_NODES) * CAP * 4);

    hipMemsetAsync(cursor, 0, size_t(N_NODES) * 4, stream);
    hipMemsetAsync(d_out, 0, 32 * 4, stream);

    // CSR bucket fill (R8 form) + weight prep tail
    fill_prep<<<FILL_B + PREP_B, 256, 0, stream>>>(ei, cursor, srclist,
        W1, W2, W3, as1, ad1, as2, ad2, as3, ad3, WtX1, WtX2, WtX3);

    // layer 1 (fp32 A, cvt in register)
    gemm_mfma<8, true><<<GEMM_B, 256, 0, stream>>>(x, WtX1, bufH, als, ald);
    agg128<<<AGG128_B, 256, 0, stream>>>(bufH, als, ald, cursor, srclist, b1, bufF);

    // layer 2
    gemm_mfma<8, false><<<GEMM_B, 256, 0, stream>>>(bufF, WtX2, bufH, als, ald);
    agg128<<<AGG128_B, 256, 0, stream>>>(bufH, als, ald, cursor, srclist, b2, bufF);

    // layer 3
    gemm_mfma<2, false><<<GEMM_B, 256, 0, stream>>>(bufF, WtX3, bufH, als, ald);
    agg32<<<AGG32_B, 256, 0, stream>>>(bufH, als, ald, cursor, srclist, b3, (float*)d_out);
}